// Round 5
// baseline (575.443 us; speedup 1.0000x reference)
//
#include <hip/hip_runtime.h>
#include <math.h>

// Problem constants
#define BATCH 65536
#define XD 362
#define ZD 100

// ws layout (bytes):
//   [0,256)                : counts[3] (int), zeroed each launch
//   [256, 786688)          : idxlist[3][65536] (int)
//   [786688, +13107200)    : z [B][100] bf16
//   [13893888, +2007040)   : repacked bf16 weights in MFMA B-fragment order
#define WS_IDX_OFF 256
#define WS_Z_OFF   786688
#define WS_WT_OFF  13893888

// Weight offsets in bf16 elements. Fragment order: for each matrix,
// index = ((ct*NKT + kt)*64 + lane)*8 + j, where the fragment element is
// B[k = kt*32 + (lane>>4)*8 + j][n = ct*16 + (lane&15)], zero-padded to Kp,Np.
#define OFF_W1 0        // Kp=384 Np=256
#define OFF_W2 98304    // Kp=256 Np=256
#define OFF_W3 163840   // Kp=224 Np=128
#define OFF_E1 192512   // 3 x Kp=128 Np=192, stride 24576
#define OFF_E2 266240   // 3 x Kp=160 Np=256, stride 40960
#define OFF_E3 389120   // 3 x Kp=256 Np=320, stride 81920
#define OFF_E4 634880   // 3 x Kp=320 Np=384, stride 122880

typedef short short8 __attribute__((ext_vector_type(8)));
typedef float f32x4 __attribute__((ext_vector_type(4)));

__device__ __forceinline__ unsigned short f2bf(float f) {
    union { float f; unsigned u; } v; v.f = f;
    unsigned u = v.u + 0x7fffu + ((v.u >> 16) & 1u);  // RNE
    return (unsigned short)(u >> 16);
}

// ---------------- repack: W[K][N] fp32 -> bf16 MFMA B-fragment order --------
__global__ __launch_bounds__(256) void repack_kernel(
    const float* __restrict__ W1, const float* __restrict__ W2,
    const float* __restrict__ W3, const float* __restrict__ eW1,
    const float* __restrict__ eW2, const float* __restrict__ eW3,
    const float* __restrict__ eW4, unsigned short* __restrict__ dst) {
    int m = blockIdx.y;
    const float* src; int K, N, Kp, Np; size_t off;
    if (m == 0)      { src = W1; K = 362; N = 256; Kp = 384; Np = 256; off = OFF_W1; }
    else if (m == 1) { src = W2; K = 256; N = 200; Kp = 256; Np = 256; off = OFF_W2; }
    else if (m == 2) { src = W3; K = 200; N = 100; Kp = 224; Np = 128; off = OFF_W3; }
    else if (m <= 5) { int e = m - 3;  src = eW1 + e * 15000;  K = 100; N = 150; Kp = 128; Np = 192; off = OFF_E1 + (size_t)e * 24576; }
    else if (m <= 8) { int e = m - 6;  src = eW2 + e * 37500;  K = 150; N = 250; Kp = 160; Np = 256; off = OFF_E2 + (size_t)e * 40960; }
    else if (m <= 11){ int e = m - 9;  src = eW3 + e * 75000;  K = 250; N = 300; Kp = 256; Np = 320; off = OFF_E3 + (size_t)e * 81920; }
    else             { int e = m - 12; src = eW4 + e * 108600; K = 300; N = 362; Kp = 320; Np = 384; off = OFF_E4 + (size_t)e * 122880; }
    int nkt = Kp / 32;
    int total = Kp * Np;
    for (int i = blockIdx.x * 256 + threadIdx.x; i < total; i += gridDim.x * 256) {
        int j = i & 7, lane = (i >> 3) & 63, t = i >> 9;
        int kt = t % nkt, ct = t / nkt;
        int k = kt * 32 + (lane >> 4) * 8 + j;
        int n = ct * 16 + (lane & 15);
        float v = (k < K && n < N) ? src[(size_t)k * N + n] : 0.0f;
        dst[off + i] = f2bf(v);
    }
}

// ---------------- bucket rows by expert (wave-aggregated atomics) -----------
__global__ __launch_bounds__(256) void bucket_kernel(const int* __restrict__ a,
                                                     int* __restrict__ counts,
                                                     int* __restrict__ idxlist) {
    int b = blockIdx.x * 256 + threadIdx.x;
    int lane = threadIdx.x & 63;
    int e = a[b];
    unsigned long long below = (lane == 63) ? ~0ull >> 1
                                            : ((1ull << (lane + 1)) - 1ull) >> 1;
    int pos = 0;
#pragma unroll
    for (int ee = 0; ee < 3; ++ee) {
        unsigned long long mask = __ballot(e == ee);
        if (e == ee) {
            int leader = __ffsll((long long)mask) - 1;
            int base = 0;
            if (lane == leader)
                base = atomicAdd(&counts[ee], __popcll(mask));
            base = __shfl(base, leader, 64);
            pos = base + __popcll(mask & below);
        }
    }
    idxlist[e * BATCH + pos] = b;
}

// Generic MFMA layer over a 64-row LDS tile (4 row-tiles of 16).
// in: bf16 LDS [64][LDI] (zero-padded to KP). out: bf16 LDS [64][LDO],
// relu(acc+bias), cols n<NSTORE written, zeros for n>=NREAL.
// Wave wv owns col-tiles {wv, wv+4, ...}. A-frag: [m=lane&15][k=quad*8+j];
// B-frag from pre-swizzled global; C/D: row=quad*4+reg, col=lane&15.
template <int KP, int NP, int LDI, int LDO, int NREAL, int NSTORE>
__device__ __forceinline__ void mfma_layer64(
    const unsigned short* __restrict__ Wf, const float* __restrict__ bias,
    const unsigned short* __restrict__ inL, unsigned short* __restrict__ outL,
    int wv, int lane) {
    constexpr int NKT = KP / 32, NCT = NP / 16, CPW = NCT / 4;
    const int quad = lane >> 4, l15 = lane & 15;
    f32x4 acc[CPW][4];
#pragma unroll
    for (int i = 0; i < CPW; ++i)
#pragma unroll
        for (int rt = 0; rt < 4; ++rt)
            acc[i][rt] = (f32x4){0.f, 0.f, 0.f, 0.f};
    const unsigned short* ap = inL + l15 * LDI + quad * 8;
#pragma unroll 2
    for (int kt = 0; kt < NKT; ++kt) {
        short8 a[4];
#pragma unroll
        for (int rt = 0; rt < 4; ++rt)
            a[rt] = *(const short8*)(ap + rt * 16 * LDI + kt * 32);
        short8 bf[CPW];
#pragma unroll
        for (int i = 0; i < CPW; ++i)
            bf[i] = *(const short8*)(Wf + ((size_t)((wv + 4 * i) * NKT + kt) * 64 + lane) * 8);
#pragma unroll
        for (int i = 0; i < CPW; ++i)
#pragma unroll
            for (int rt = 0; rt < 4; ++rt)
                acc[i][rt] = __builtin_amdgcn_mfma_f32_16x16x32_bf16(a[rt], bf[i], acc[i][rt], 0, 0, 0);
    }
#pragma unroll
    for (int i = 0; i < CPW; ++i) {
        int n = (wv + 4 * i) * 16 + l15;
        if (n < NSTORE) {
            float bv = (n < NREAL) ? bias[n] : 0.f;
#pragma unroll
            for (int rt = 0; rt < 4; ++rt)
#pragma unroll
                for (int r = 0; r < 4; ++r) {
                    int row = rt * 16 + quad * 4 + r;
                    float v = fmaxf(acc[i][rt][r] + bv, 0.f);
                    outL[row * LDO + n] = (n < NREAL) ? f2bf(v) : (unsigned short)0;
                }
        }
    }
}

// ---------------- fused encoder: x -> z (bf16), 64 rows/block ---------------
__global__ __launch_bounds__(256, 2) void encoder_kernel(
    const float* __restrict__ x, const unsigned short* __restrict__ Wts,
    const float* __restrict__ b1, const float* __restrict__ b2,
    const float* __restrict__ b3, unsigned short* __restrict__ z) {
    __shared__ unsigned short bufX[64 * 264];  // x chunk (ld200) then h2 (ld264)
    __shared__ unsigned short bufB[64 * 264];  // h1 (ld264, Kp256)
    int tid = threadIdx.x;
    int wv = tid >> 6, lane = tid & 63;
    const int quad = lane >> 4, l15 = lane & 15;
    int rowbase = blockIdx.x * 64;

    // ---- L1: Kp=384 (NKT=12), Np=256 (CPW=4), K-chunked (2 x 192) ----------
    f32x4 acc[4][4];
#pragma unroll
    for (int i = 0; i < 4; ++i)
#pragma unroll
        for (int rt = 0; rt < 4; ++rt) acc[i][rt] = (f32x4){0.f, 0.f, 0.f, 0.f};
    unsigned* dX = (unsigned*)bufX;
    const unsigned short* W1f = Wts + OFF_W1;
#pragma unroll
    for (int ch = 0; ch < 2; ++ch) {
        if (ch) __syncthreads();   // drain chunk-0 A-frag reads before restage
        for (int i = tid; i < 64 * 100; i += 256) {
            int r = i / 100, c = i - r * 100;
            int kk = ch * 96 + c;   // global bf16-pair index
            unsigned pk = 0u;
            if (c < 96 && kk < 181) {
                float2 v = *(const float2*)(x + (size_t)(rowbase + r) * 362 + 2 * kk);
                pk = (unsigned)f2bf(v.x) | ((unsigned)f2bf(v.y) << 16);
            }
            dX[r * 100 + c] = pk;
        }
        __syncthreads();
        const unsigned short* ap = bufX + l15 * 200 + quad * 8;
#pragma unroll
        for (int kt = 0; kt < 6; ++kt) {
            int ktg = ch * 6 + kt;
            short8 a[4];
#pragma unroll
            for (int rt = 0; rt < 4; ++rt)
                a[rt] = *(const short8*)(ap + rt * 16 * 200 + kt * 32);
            short8 bf[4];
#pragma unroll
            for (int i = 0; i < 4; ++i)
                bf[i] = *(const short8*)(W1f + ((size_t)((wv + 4 * i) * 12 + ktg) * 64 + lane) * 8);
#pragma unroll
            for (int i = 0; i < 4; ++i)
#pragma unroll
                for (int rt = 0; rt < 4; ++rt)
                    acc[i][rt] = __builtin_amdgcn_mfma_f32_16x16x32_bf16(a[rt], bf[i], acc[i][rt], 0, 0, 0);
        }
    }
    __syncthreads();
    // epilogue: h1 = relu(acc + b1) -> bufB (ld 264, all 256 cols real)
#pragma unroll
    for (int i = 0; i < 4; ++i) {
        int n = (wv + 4 * i) * 16 + l15;
        float bv = b1[n];
#pragma unroll
        for (int rt = 0; rt < 4; ++rt)
#pragma unroll
            for (int r = 0; r < 4; ++r) {
                int row = rt * 16 + quad * 4 + r;
                bufB[row * 264 + n] = f2bf(fmaxf(acc[i][rt][r] + bv, 0.f));
            }
    }
    __syncthreads();
    // ---- L2: 256 -> 200 (store 224 cols, zero-padded) ----------------------
    mfma_layer64<256, 256, 264, 264, 200, 224>(Wts + OFF_W2, b2, bufB, bufX, wv, lane);
    __syncthreads();
    // ---- L3: Kp=224 (NKT=7), Np=128 (CPW=2), sigmoid -> z ------------------
    {
        const unsigned short* W3f = Wts + OFF_W3;
        f32x4 acc3[2][4];
#pragma unroll
        for (int i = 0; i < 2; ++i)
#pragma unroll
            for (int rt = 0; rt < 4; ++rt) acc3[i][rt] = (f32x4){0.f, 0.f, 0.f, 0.f};
        const unsigned short* ap = bufX + l15 * 264 + quad * 8;
#pragma unroll 2
        for (int kt = 0; kt < 7; ++kt) {
            short8 a[4];
#pragma unroll
            for (int rt = 0; rt < 4; ++rt)
                a[rt] = *(const short8*)(ap + rt * 16 * 264 + kt * 32);
            short8 bf[2];
#pragma unroll
            for (int i = 0; i < 2; ++i)
                bf[i] = *(const short8*)(W3f + ((size_t)((wv + 4 * i) * 7 + kt) * 64 + lane) * 8);
#pragma unroll
            for (int i = 0; i < 2; ++i)
#pragma unroll
                for (int rt = 0; rt < 4; ++rt)
                    acc3[i][rt] = __builtin_amdgcn_mfma_f32_16x16x32_bf16(a[rt], bf[i], acc3[i][rt], 0, 0, 0);
        }
#pragma unroll
        for (int i = 0; i < 2; ++i) {
            int n = (wv + 4 * i) * 16 + l15;
            if (n < 100) {
                float bv = b3[n];
#pragma unroll
                for (int rt = 0; rt < 4; ++rt)
#pragma unroll
                    for (int r = 0; r < 4; ++r) {
                        int row = rowbase + rt * 16 + quad * 4 + r;
                        float s = 1.0f / (1.0f + expf(-(acc3[i][rt][r] + bv)));
                        z[(size_t)row * 100 + n] = f2bf(s);
                    }
            }
        }
    }
}

// ---------------- fused expert chain + loss, 64 rows/block ------------------
__global__ __launch_bounds__(256, 2) void expert_kernel(
    const unsigned short* __restrict__ z, const int* __restrict__ counts,
    const int* __restrict__ idxlist, const unsigned short* __restrict__ Wts,
    const float* __restrict__ eb1, const float* __restrict__ eb2,
    const float* __restrict__ eb3, const float* __restrict__ eb4,
    const float* __restrict__ x, const float* __restrict__ xn,
    float* __restrict__ out) {
    int e = blockIdx.y;
    int cnt = counts[e];
    int start = blockIdx.x * 64;
    if (start >= cnt) return;
    int nrows = min(64, cnt - start);

    __shared__ unsigned short bufA[64 * 264];  // z (ld136) then h2 (ld264)
    __shared__ unsigned short bufB[64 * 328];  // h1 (ld168) then h3 (ld328)
    __shared__ int s_idx[64];
    __shared__ float s_part[4];

    int tid = threadIdx.x;
    int wv = tid >> 6, lane = tid & 63;
    const int quad = lane >> 4, l15 = lane & 15;

    if (tid < 64)
        s_idx[tid] = (tid < nrows) ? idxlist[e * BATCH + start + tid] : -1;
    __syncthreads();
    // gather z rows (bf16 pairs as dwords), ld 136 (68 dwords), pad k>=100
    {
        unsigned* dA = (unsigned*)bufA;
        const unsigned* zd = (const unsigned*)z;
        for (int i = tid; i < 64 * 68; i += 256) {
            int r = i / 68, c = i - r * 68;
            int b = s_idx[r];
            dA[r * 68 + c] = (b >= 0 && c < 50) ? zd[(size_t)b * 50 + c] : 0u;
        }
    }
    __syncthreads();
    mfma_layer64<128, 192, 136, 168, 150, 160>(Wts + OFF_E1 + (size_t)e * 24576,
                                               eb1 + e * 150, bufA, bufB, wv, lane);
    __syncthreads();
    mfma_layer64<160, 256, 168, 264, 250, 256>(Wts + OFF_E2 + (size_t)e * 40960,
                                               eb2 + e * 250, bufB, bufA, wv, lane);
    __syncthreads();
    mfma_layer64<256, 320, 264, 328, 300, 320>(Wts + OFF_E3 + (size_t)e * 81920,
                                               eb3 + e * 300, bufA, bufB, wv, lane);
    __syncthreads();

    // L4: Kp=320 (NKT=10), Np=384 (CPW=6), fused with loss from accumulators
    float lacc = 0.0f;
    {
        constexpr int NKT = 10, CPW = 6;
        const unsigned short* Wf = Wts + OFF_E4 + (size_t)e * 122880;
        const float* bias4 = eb4 + (size_t)e * 362;
        f32x4 acc[CPW][4];
#pragma unroll
        for (int i = 0; i < CPW; ++i)
#pragma unroll
            for (int rt = 0; rt < 4; ++rt) acc[i][rt] = (f32x4){0.f, 0.f, 0.f, 0.f};
        const unsigned short* ap = bufB + l15 * 328 + quad * 8;
#pragma unroll 2
        for (int kt = 0; kt < NKT; ++kt) {
            short8 a[4];
#pragma unroll
            for (int rt = 0; rt < 4; ++rt)
                a[rt] = *(const short8*)(ap + rt * 16 * 328 + kt * 32);
            short8 bf[CPW];
#pragma unroll
            for (int i = 0; i < CPW; ++i)
                bf[i] = *(const short8*)(Wf + ((size_t)((wv + 4 * i) * NKT + kt) * 64 + lane) * 8);
#pragma unroll
            for (int i = 0; i < CPW; ++i)
#pragma unroll
                for (int rt = 0; rt < 4; ++rt)
                    acc[i][rt] = __builtin_amdgcn_mfma_f32_16x16x32_bf16(a[rt], bf[i], acc[i][rt], 0, 0, 0);
        }
        const float WC0 = 1.0f / 65536.0f;
        const float WCR = 1.0f / (361.0f * 65536.0f);
#pragma unroll
        for (int i = 0; i < CPW; ++i) {
            int n = (wv + 4 * i) * 16 + l15;
            if (n < 362) {
                float bv = bias4[n];
                float wgt = (n == 0) ? WC0 : WCR;
#pragma unroll
                for (int rt = 0; rt < 4; ++rt) {
                    int row = rt * 16 + quad * 4;
#pragma unroll
                    for (int r = 0; r < 4; ++r) {
                        int b = s_idx[row + r];
                        if (b >= 0) {
                            float pred = acc[i][rt][r] + bv;
                            float delta = xn[(size_t)b * 362 + n] - x[(size_t)b * 362 + n];
                            float err = pred - delta;
                            lacc += wgt * err * err;
                        }
                    }
                }
            }
        }
    }
    // block reduction -> atomicAdd
    for (int off = 32; off; off >>= 1)
        lacc += __shfl_down(lacc, off, 64);
    if ((tid & 63) == 0) s_part[wv] = lacc;
    __syncthreads();
    if (tid == 0)
        atomicAdd(out, s_part[0] + s_part[1] + s_part[2] + s_part[3]);
}

extern "C" void kernel_launch(void* const* d_in, const int* in_sizes, int n_in,
                              void* d_out, int out_size, void* d_ws, size_t ws_size,
                              hipStream_t stream) {
    const float* x   = (const float*)d_in[0];
    const float* xn  = (const float*)d_in[1];
    const int*   a   = (const int*)d_in[2];
    const float* W1  = (const float*)d_in[3];
    const float* b1  = (const float*)d_in[4];
    const float* W2  = (const float*)d_in[5];
    const float* b2  = (const float*)d_in[6];
    const float* W3  = (const float*)d_in[7];
    const float* b3  = (const float*)d_in[8];
    const float* eW1 = (const float*)d_in[9];
    const float* eb1 = (const float*)d_in[10];
    const float* eW2 = (const float*)d_in[11];
    const float* eb2 = (const float*)d_in[12];
    const float* eW3 = (const float*)d_in[13];
    const float* eb3 = (const float*)d_in[14];
    const float* eW4 = (const float*)d_in[15];
    const float* eb4 = (const float*)d_in[16];

    char* ws = (char*)d_ws;
    int* counts           = (int*)ws;
    int* idxlist          = (int*)(ws + WS_IDX_OFF);
    unsigned short* z     = (unsigned short*)(ws + WS_Z_OFF);
    unsigned short* Wts   = (unsigned short*)(ws + WS_WT_OFF);

    hipMemsetAsync(counts, 0, 256, stream);
    hipMemsetAsync(d_out, 0, sizeof(float), stream);

    repack_kernel<<<dim3(32, 15), 256, 0, stream>>>(W1, W2, W3, eW1, eW2, eW3, eW4, Wts);
    bucket_kernel<<<BATCH / 256, 256, 0, stream>>>(a, counts, idxlist);
    encoder_kernel<<<BATCH / 64, 256, 0, stream>>>(x, Wts, b1, b2, b3, z);
    expert_kernel<<<dim3(BATCH / 64, 3), 256, 0, stream>>>(
        z, counts, idxlist, Wts, eb1, eb2, eb3, eb4, x, xn, (float*)d_out);
}

// Round 6
// 478.162 us; speedup vs baseline: 1.2034x; 1.2034x over previous
//
#include <hip/hip_runtime.h>
#include <math.h>

// Problem constants
#define BATCH 65536
#define XD 362
#define ZD 100

// ws layout (bytes):
//   [0,256)                : counts[3] (int), zeroed each launch
//   [256, 786688)          : idxlist[3][65536] (int)
//   [786688, +13107200)    : z [B][100] bf16
//   [13893888, +2007040)   : repacked bf16 weights in MFMA B-fragment order
#define WS_IDX_OFF 256
#define WS_Z_OFF   786688
#define WS_WT_OFF  13893888

// Weight offsets in bf16 elements. Fragment order: for each matrix,
// index = ((ct*NKT + kt)*64 + lane)*8 + j, where the fragment element is
// B[k = kt*32 + (lane>>4)*8 + j][n = ct*16 + (lane&15)], zero-padded to Kp,Np.
#define OFF_W1 0        // Kp=384 Np=256
#define OFF_W2 98304    // Kp=256 Np=256
#define OFF_W3 163840   // Kp=224 Np=128
#define OFF_E1 192512   // 3 x Kp=128 Np=192, stride 24576
#define OFF_E2 266240   // 3 x Kp=160 Np=256, stride 40960
#define OFF_E3 389120   // 3 x Kp=256 Np=320, stride 81920
#define OFF_E4 634880   // 3 x Kp=320 Np=384, stride 122880

typedef short short8 __attribute__((ext_vector_type(8)));
typedef float f32x4 __attribute__((ext_vector_type(4)));

__device__ __forceinline__ unsigned short f2bf(float f) {
    union { float f; unsigned u; } v; v.f = f;
    unsigned u = v.u + 0x7fffu + ((v.u >> 16) & 1u);  // RNE
    return (unsigned short)(u >> 16);
}

// ---------------- repack: W[K][N] fp32 -> bf16 MFMA B-fragment order --------
__global__ __launch_bounds__(256) void repack_kernel(
    const float* __restrict__ W1, const float* __restrict__ W2,
    const float* __restrict__ W3, const float* __restrict__ eW1,
    const float* __restrict__ eW2, const float* __restrict__ eW3,
    const float* __restrict__ eW4, unsigned short* __restrict__ dst) {
    int m = blockIdx.y;
    const float* src; int K, N, Kp, Np; size_t off;
    if (m == 0)      { src = W1; K = 362; N = 256; Kp = 384; Np = 256; off = OFF_W1; }
    else if (m == 1) { src = W2; K = 256; N = 200; Kp = 256; Np = 256; off = OFF_W2; }
    else if (m == 2) { src = W3; K = 200; N = 100; Kp = 224; Np = 128; off = OFF_W3; }
    else if (m <= 5) { int e = m - 3;  src = eW1 + e * 15000;  K = 100; N = 150; Kp = 128; Np = 192; off = OFF_E1 + (size_t)e * 24576; }
    else if (m <= 8) { int e = m - 6;  src = eW2 + e * 37500;  K = 150; N = 250; Kp = 160; Np = 256; off = OFF_E2 + (size_t)e * 40960; }
    else if (m <= 11){ int e = m - 9;  src = eW3 + e * 75000;  K = 250; N = 300; Kp = 256; Np = 320; off = OFF_E3 + (size_t)e * 81920; }
    else             { int e = m - 12; src = eW4 + e * 108600; K = 300; N = 362; Kp = 320; Np = 384; off = OFF_E4 + (size_t)e * 122880; }
    int nkt = Kp / 32;
    int total = Kp * Np;
    for (int i = blockIdx.x * 256 + threadIdx.x; i < total; i += gridDim.x * 256) {
        int j = i & 7, lane = (i >> 3) & 63, t = i >> 9;
        int kt = t % nkt, ct = t / nkt;
        int k = kt * 32 + (lane >> 4) * 8 + j;
        int n = ct * 16 + (lane & 15);
        float v = (k < K && n < N) ? src[(size_t)k * N + n] : 0.0f;
        dst[off + i] = f2bf(v);
    }
}

// ---------------- bucket rows by expert (wave-aggregated atomics) -----------
__global__ __launch_bounds__(256) void bucket_kernel(const int* __restrict__ a,
                                                     int* __restrict__ counts,
                                                     int* __restrict__ idxlist) {
    int b = blockIdx.x * 256 + threadIdx.x;
    int lane = threadIdx.x & 63;
    int e = a[b];
    unsigned long long below = (lane == 63) ? ~0ull >> 1
                                            : ((1ull << (lane + 1)) - 1ull) >> 1;
    int pos = 0;
#pragma unroll
    for (int ee = 0; ee < 3; ++ee) {
        unsigned long long mask = __ballot(e == ee);
        if (e == ee) {
            int leader = __ffsll((long long)mask) - 1;
            int base = 0;
            if (lane == leader)
                base = atomicAdd(&counts[ee], __popcll(mask));
            base = __shfl(base, leader, 64);
            pos = base + __popcll(mask & below);
        }
    }
    idxlist[e * BATCH + pos] = b;
}

// MFMA layer over a 16-row LDS tile (1 row-tile).
// in: bf16 LDS [16][LDI] (zero-padded to KP). out: bf16 LDS [16][LDO],
// relu(acc+bias), cols n<NSTORE written, zeros for n>=NREAL.
// Wave wv owns col-tiles {wv, wv+4, ...}. A-frag: [m=lane&15][k=quad*8+j];
// B-frag from pre-swizzled global; C/D: row=quad*4+reg, col=lane&15.
template <int KP, int NP, int LDI, int LDO, int NREAL, int NSTORE>
__device__ __forceinline__ void mfma_layer16(
    const unsigned short* __restrict__ Wf, const float* __restrict__ bias,
    const unsigned short* __restrict__ inL, unsigned short* __restrict__ outL,
    int wv, int lane) {
    constexpr int NKT = KP / 32, NCT = NP / 16, CPW = NCT / 4;
    const int quad = lane >> 4, l15 = lane & 15;
    f32x4 acc[CPW];
#pragma unroll
    for (int i = 0; i < CPW; ++i) acc[i] = (f32x4){0.f, 0.f, 0.f, 0.f};
    const unsigned short* ap = inL + l15 * LDI + quad * 8;
#pragma unroll
    for (int kt = 0; kt < NKT; ++kt) {
        short8 a = *(const short8*)(ap + kt * 32);
        short8 bf[CPW];
#pragma unroll
        for (int i = 0; i < CPW; ++i)
            bf[i] = *(const short8*)(Wf + ((size_t)((wv + 4 * i) * NKT + kt) * 64 + lane) * 8);
#pragma unroll
        for (int i = 0; i < CPW; ++i)
            acc[i] = __builtin_amdgcn_mfma_f32_16x16x32_bf16(a, bf[i], acc[i], 0, 0, 0);
    }
#pragma unroll
    for (int i = 0; i < CPW; ++i) {
        int n = (wv + 4 * i) * 16 + l15;
        if (n < NSTORE) {
            float bv = (n < NREAL) ? bias[n] : 0.f;
#pragma unroll
            for (int r = 0; r < 4; ++r) {
                int row = quad * 4 + r;
                float v = fmaxf(acc[i][r] + bv, 0.f);
                outL[row * LDO + n] = (n < NREAL) ? f2bf(v) : (unsigned short)0;
            }
        }
    }
}

// ---------------- fused encoder: x -> z (bf16), 16 rows/block ---------------
__global__ __launch_bounds__(256, 6) void encoder_kernel(
    const float* __restrict__ x, const unsigned short* __restrict__ Wts,
    const float* __restrict__ b1, const float* __restrict__ b2,
    const float* __restrict__ b3, unsigned short* __restrict__ z) {
    __shared__ unsigned short bufX[16 * 392];  // x (ld392,Kp384) then h2 (ld264)
    __shared__ unsigned short bufB[16 * 264];  // h1 (ld264, Kp256)
    int tid = threadIdx.x;
    int wv = tid >> 6, lane = tid & 63;
    const int quad = lane >> 4, l15 = lane & 15;
    int rowbase = blockIdx.x * 16;

    // stage x -> bf16 pairs, ld 392 (196 dwords), zero-pad k>=362
    unsigned* dX = (unsigned*)bufX;
    for (int i = tid; i < 16 * 196; i += 256) {
        int r = i / 196, c = i - r * 196;
        unsigned pk = 0u;
        if (c < 181) {
            float2 v = *(const float2*)(x + (size_t)(rowbase + r) * 362 + 2 * c);
            pk = (unsigned)f2bf(v.x) | ((unsigned)f2bf(v.y) << 16);
        }
        dX[r * 196 + c] = pk;
    }
    __syncthreads();
    mfma_layer16<384, 256, 392, 264, 256, 256>(Wts + OFF_W1, b1, bufX, bufB, wv, lane);
    __syncthreads();
    mfma_layer16<256, 256, 264, 264, 200, 224>(Wts + OFF_W2, b2, bufB, bufX, wv, lane);
    __syncthreads();
    // L3: Kp=224 (NKT=7), Np=128 (CPW=2), sigmoid -> z
    {
        const unsigned short* W3f = Wts + OFF_W3;
        f32x4 acc3[2];
#pragma unroll
        for (int i = 0; i < 2; ++i) acc3[i] = (f32x4){0.f, 0.f, 0.f, 0.f};
        const unsigned short* ap = bufX + l15 * 264 + quad * 8;
#pragma unroll
        for (int kt = 0; kt < 7; ++kt) {
            short8 a = *(const short8*)(ap + kt * 32);
            short8 bf[2];
#pragma unroll
            for (int i = 0; i < 2; ++i)
                bf[i] = *(const short8*)(W3f + ((size_t)((wv + 4 * i) * 7 + kt) * 64 + lane) * 8);
#pragma unroll
            for (int i = 0; i < 2; ++i)
                acc3[i] = __builtin_amdgcn_mfma_f32_16x16x32_bf16(a, bf[i], acc3[i], 0, 0, 0);
        }
#pragma unroll
        for (int i = 0; i < 2; ++i) {
            int n = (wv + 4 * i) * 16 + l15;
            if (n < 100) {
                float bv = b3[n];
#pragma unroll
                for (int r = 0; r < 4; ++r) {
                    int row = rowbase + quad * 4 + r;
                    float s = 1.0f / (1.0f + expf(-(acc3[i][r] + bv)));
                    z[(size_t)row * 100 + n] = f2bf(s);
                }
            }
        }
    }
}

// ---------------- fused expert chain + loss, 16 rows/block ------------------
__global__ __launch_bounds__(256, 6) void expert_kernel(
    const unsigned short* __restrict__ z, const int* __restrict__ counts,
    const int* __restrict__ idxlist, const unsigned short* __restrict__ Wts,
    const float* __restrict__ eb1, const float* __restrict__ eb2,
    const float* __restrict__ eb3, const float* __restrict__ eb4,
    const float* __restrict__ x, const float* __restrict__ xn,
    float* __restrict__ out) {
    int e = blockIdx.y;
    int cnt = counts[e];
    int start = blockIdx.x * 16;
    if (start >= cnt) return;
    int nrows = min(16, cnt - start);

    __shared__ unsigned short bufA[16 * 264];  // z (ld136) then h2 (ld264)
    __shared__ unsigned short bufB[16 * 328];  // h1 (ld168) then h3 (ld328)
    __shared__ int s_idx[16];
    __shared__ float s_part[4];

    int tid = threadIdx.x;
    int wv = tid >> 6, lane = tid & 63;
    const int quad = lane >> 4, l15 = lane & 15;

    if (tid < 16)
        s_idx[tid] = (tid < nrows) ? idxlist[e * BATCH + start + tid] : -1;
    __syncthreads();
    // gather z rows (bf16 pairs as dwords), ld 136 (68 dwords), pad k>=100
    {
        unsigned* dA = (unsigned*)bufA;
        const unsigned* zd = (const unsigned*)z;
        for (int i = tid; i < 16 * 68; i += 256) {
            int r = i / 68, c = i - r * 68;
            int b = s_idx[r];
            dA[r * 68 + c] = (b >= 0 && c < 50) ? zd[(size_t)b * 50 + c] : 0u;
        }
    }
    __syncthreads();
    mfma_layer16<128, 192, 136, 168, 150, 160>(Wts + OFF_E1 + (size_t)e * 24576,
                                               eb1 + e * 150, bufA, bufB, wv, lane);
    __syncthreads();
    mfma_layer16<160, 256, 168, 264, 250, 256>(Wts + OFF_E2 + (size_t)e * 40960,
                                               eb2 + e * 250, bufB, bufA, wv, lane);
    __syncthreads();
    mfma_layer16<256, 320, 264, 328, 300, 320>(Wts + OFF_E3 + (size_t)e * 81920,
                                               eb3 + e * 300, bufA, bufB, wv, lane);
    __syncthreads();

    // L4: Kp=320 (NKT=10), Np=384 (CPW=6), fused with loss from accumulators
    float lacc = 0.0f;
    {
        constexpr int NKT = 10, CPW = 6;
        const unsigned short* Wf = Wts + OFF_E4 + (size_t)e * 122880;
        const float* bias4 = eb4 + (size_t)e * 362;
        f32x4 acc[CPW];
#pragma unroll
        for (int i = 0; i < CPW; ++i) acc[i] = (f32x4){0.f, 0.f, 0.f, 0.f};
        const unsigned short* ap = bufB + l15 * 328 + quad * 8;
#pragma unroll
        for (int kt = 0; kt < NKT; ++kt) {
            short8 a = *(const short8*)(ap + kt * 32);
            short8 bf[CPW];
#pragma unroll
            for (int i = 0; i < CPW; ++i)
                bf[i] = *(const short8*)(Wf + ((size_t)((wv + 4 * i) * NKT + kt) * 64 + lane) * 8);
#pragma unroll
            for (int i = 0; i < CPW; ++i)
                acc[i] = __builtin_amdgcn_mfma_f32_16x16x32_bf16(a, bf[i], acc[i], 0, 0, 0);
        }
        const float WC0 = 1.0f / 65536.0f;
        const float WCR = 1.0f / (361.0f * 65536.0f);
#pragma unroll
        for (int i = 0; i < CPW; ++i) {
            int n = (wv + 4 * i) * 16 + l15;
            if (n < 362) {
                float bv = bias4[n];
                float wgt = (n == 0) ? WC0 : WCR;
#pragma unroll
                for (int r = 0; r < 4; ++r) {
                    int b = s_idx[quad * 4 + r];
                    if (b >= 0) {
                        float pred = acc[i][r] + bv;
                        float delta = xn[(size_t)b * 362 + n] - x[(size_t)b * 362 + n];
                        float err = pred - delta;
                        lacc += wgt * err * err;
                    }
                }
            }
        }
    }
    // block reduction -> atomicAdd
    for (int off = 32; off; off >>= 1)
        lacc += __shfl_down(lacc, off, 64);
    if ((tid & 63) == 0) s_part[wv] = lacc;
    __syncthreads();
    if (tid == 0)
        atomicAdd(out, s_part[0] + s_part[1] + s_part[2] + s_part[3]);
}

extern "C" void kernel_launch(void* const* d_in, const int* in_sizes, int n_in,
                              void* d_out, int out_size, void* d_ws, size_t ws_size,
                              hipStream_t stream) {
    const float* x   = (const float*)d_in[0];
    const float* xn  = (const float*)d_in[1];
    const int*   a   = (const int*)d_in[2];
    const float* W1  = (const float*)d_in[3];
    const float* b1  = (const float*)d_in[4];
    const float* W2  = (const float*)d_in[5];
    const float* b2  = (const float*)d_in[6];
    const float* W3  = (const float*)d_in[7];
    const float* b3  = (const float*)d_in[8];
    const float* eW1 = (const float*)d_in[9];
    const float* eb1 = (const float*)d_in[10];
    const float* eW2 = (const float*)d_in[11];
    const float* eb2 = (const float*)d_in[12];
    const float* eW3 = (const float*)d_in[13];
    const float* eb3 = (const float*)d_in[14];
    const float* eW4 = (const float*)d_in[15];
    const float* eb4 = (const float*)d_in[16];

    char* ws = (char*)d_ws;
    int* counts           = (int*)ws;
    int* idxlist          = (int*)(ws + WS_IDX_OFF);
    unsigned short* z     = (unsigned short*)(ws + WS_Z_OFF);
    unsigned short* Wts   = (unsigned short*)(ws + WS_WT_OFF);

    hipMemsetAsync(counts, 0, 256, stream);
    hipMemsetAsync(d_out, 0, sizeof(float), stream);

    repack_kernel<<<dim3(32, 15), 256, 0, stream>>>(W1, W2, W3, eW1, eW2, eW3, eW4, Wts);
    bucket_kernel<<<BATCH / 256, 256, 0, stream>>>(a, counts, idxlist);
    encoder_kernel<<<BATCH / 16, 256, 0, stream>>>(x, Wts, b1, b2, b3, z);
    expert_kernel<<<dim3(BATCH / 16, 3), 256, 0, stream>>>(
        z, counts, idxlist, Wts, eb1, eb2, eb3, eb4, x, xn, (float*)d_out);
}